// Round 18
// baseline (89.417 us; speedup 1.0000x reference)
//
#include <hip/hip_runtime.h>
#include <hip/hip_fp8.h>

typedef int v8i __attribute__((ext_vector_type(8)));
typedef float f32x4 __attribute__((ext_vector_type(4)));

#define N_TOTAL 262144
#define D 128
#define K_TOTAL 1024
#define BN 128
#define NBLK (N_TOTAL / BN)  // 2048
#define TILEB 8192  // 64 centroids x 128 dims x 1 B fp8, 16x16x128-operand order
#define NT 16

__device__ __forceinline__ unsigned f2fp8_em(float x) {
  return (unsigned)__hip_fp8_e4m3(x).__x;
}

// Kernel 1: codebook fp32 -> fp8 e4m3 (HW cvt_pk) in 16x16x128 B-operand
// order; nm2[k] = -0.5*||m||^2 exact fp32. (verified r17: absmax 0.0)
__global__ void prep_means(const float* __restrict__ means,
                           unsigned char* __restrict__ mbf8,
                           float* __restrict__ nm2) {
  int k = blockIdx.x, t = threadIdx.x;  // 1024 blocks x 64 threads
  int ts = k >> 6, c64 = k & 63;
  int cgc = c64 >> 4, c = c64 & 15;
  unsigned char* tb = mbf8 + ts * TILEB + cgc * 2048;
  float v0 = means[k * D + 2 * t];
  float v1 = means[k * D + 2 * t + 1];
  int d0 = 2 * t;
  int kq = d0 >> 5, rem0 = d0 & 31;
  int pk = __builtin_amdgcn_cvt_pk_fp8_f32(v0, v1, 0, false);
  *(unsigned short*)(tb + (kq * 16 + c) * 32 + rem0) =
      (unsigned short)(pk & 0xFFFF);
  float s = v0 * v0 + v1 * v1;
#pragma unroll
  for (int m = 32; m; m >>= 1) s += __shfl_down(s, m, 64);
  if (t == 0) nm2[k] = -0.5f * s;
}

// Kernel 1b: X fp32 -> fp8 packed in EXACT A-operand order + exact x2[n].
// Row n, dim d -> xp[(n>>4)*2048 + (d>>5)*512 + (n&15)*32 + (d&31)]
// (so MFMA lane l of row-group g reads 32B at group*2048 + l*32).
// Streaming kernel: conversion VALU hides under the 168 MB memory stream.
__global__ __launch_bounds__(256) void prep_x(const float* __restrict__ X,
                                              unsigned char* __restrict__ xp,
                                              float* __restrict__ x2g) {
  const int t = threadIdx.x;
  const long row = (long)blockIdx.x * BN + (t >> 1);
  const int h = t & 1;  // half-row: dims h*64 .. h*64+63
  const float* xr = X + row * D + h * 64;
  unsigned cw[16];
  float sq = 0.f;
#pragma unroll
  for (int j = 0; j < 16; ++j) {
    float4 v = *(const float4*)(xr + j * 4);
    sq = fmaf(v.x, v.x, sq);
    sq = fmaf(v.y, v.y, sq);
    sq = fmaf(v.z, v.z, sq);
    sq = fmaf(v.w, v.w, sq);
    int lo = __builtin_amdgcn_cvt_pk_fp8_f32(v.x, v.y, 0, false);
    cw[j] = (unsigned)__builtin_amdgcn_cvt_pk_fp8_f32(v.z, v.w, lo, true);
  }
  unsigned char* gb = xp + (row >> 4) * 2048 + (int)(row & 15) * 32;
#pragma unroll
  for (int q = 0; q < 2; ++q) {  // kq = h*2 + q
    uint4 a, b;
    a.x = cw[q * 8 + 0]; a.y = cw[q * 8 + 1]; a.z = cw[q * 8 + 2]; a.w = cw[q * 8 + 3];
    b.x = cw[q * 8 + 4]; b.y = cw[q * 8 + 5]; b.z = cw[q * 8 + 6]; b.w = cw[q * 8 + 7];
    unsigned char* d0 = gb + (h * 2 + q) * 512;
    *(uint4*)d0 = a;
    *(uint4*)(d0 + 16) = b;
  }
  float s2 = sq + __shfl_xor(sq, 1, 64);
  if (h == 0) x2g[row] = s2;
}

union BOp {
  uint4 q[2];
  v8i v;
};

// Kernel 2: skinny main. A pre-packed fp8 (2x 32B loads/lane), B direct from
// L1/L2 (128 KB codebook, shared stream order), nm2 direct from L1 (4 KB).
// NO conversions, NO LDS tiles, NO pre-loop barrier. loss = x2 - 2*max(score).
__global__ __launch_bounds__(256) void kmeans_main(
    const unsigned char* __restrict__ xp, const unsigned char* __restrict__ mbf8,
    const float* __restrict__ nm2, const float* __restrict__ x2g,
    float* __restrict__ partials) {
  __shared__ float wsum[4];

  const int t = threadIdx.x;
  const int l = t & 63;
  const int w = t >> 6;
  const int lr = l & 15;  // row-in-group (A) / centroid-in-group (B/C)
  const int kq = l >> 4;
  const long nbase = (long)blockIdx.x * BN;

  // ---- A fragments: 2 row-groups, 32B each, operand-order linear ----
  v8i af[2];
  {
    const unsigned char* ap =
        xp + ((long)blockIdx.x * 8 + w * 2) * 2048 + l * 32;
    BOp a0, a1;
    a0.q[0] = *(const uint4*)(ap);
    a0.q[1] = *(const uint4*)(ap + 16);
    a1.q[0] = *(const uint4*)(ap + 2048);
    a1.q[1] = *(const uint4*)(ap + 2048 + 16);
    af[0] = a0.v;
    af[1] = a1.v;
  }

  float bs[8];  // running row maxes: [g*4 + reg]
#pragma unroll
  for (int e = 0; e < 8; ++e) bs[e] = -3.402823466e38f;

  // ---- barrier-free main loop: B + nm2 direct from L1/L2 ----
  const char* bbase = (const char*)mbf8 + l * 32;
  const float* mp = nm2 + lr;
  for (int ts = 0; ts < NT; ++ts) {
    const char* tp = bbase + ts * TILEB;
#pragma unroll
    for (int cgc = 0; cgc < 4; ++cgc) {
      const char* p = tp + cgc * 2048;
      BOp bu;
      bu.q[0] = *(const uint4*)(p);
      bu.q[1] = *(const uint4*)(p + 16);
      float m2v = mp[ts * 64 + cgc * 16];
      f32x4 ci = {m2v, m2v, m2v, m2v};
#pragma unroll
      for (int g = 0; g < 2; ++g) {
        f32x4 acc = __builtin_amdgcn_mfma_scale_f32_16x16x128_f8f6f4(
            af[g], bu.v, ci, 0, 0, 0, 127, 0, 127);
#pragma unroll
        for (int e = 0; e < 4; ++e) bs[g * 4 + e] = fmaxf(bs[g * 4 + e], acc[e]);
      }
    }
  }

  // ---- per-row max across the 16 centroid-lanes, then loss contribution ----
  float lsum = 0.f;
#pragma unroll
  for (int e = 0; e < 8; ++e) {
    float m = bs[e];
#pragma unroll
    for (int s = 1; s < 16; s <<= 1) {
      float o = __shfl_xor(m, s, 64);
      m = fmaxf(m, o);
    }
    if (lr == 0) {
      int rowc = (e >> 2) * 16 + kq * 4 + (e & 3);
      lsum += x2g[nbase + w * 32 + rowc] - 2.0f * m;
    }
  }
#pragma unroll
  for (int s = 32; s; s >>= 1) lsum += __shfl_down(lsum, s, 64);
  if (l == 0) wsum[w] = lsum;
  __syncthreads();
  if (t == 0) partials[blockIdx.x] = wsum[0] + wsum[1] + wsum[2] + wsum[3];
}

// Fallback main (r16, verified): used only if ws_size < packed-X needs.
__global__ __launch_bounds__(256) void kmeans_main_fb(
    const float* __restrict__ X, const unsigned char* __restrict__ mbf8,
    const float* __restrict__ nm2, float* __restrict__ partials) {
  __shared__ float m2s[K_TOTAL];
  __shared__ float x2s[BN];
  __shared__ float wsum[4];
  const int t = threadIdx.x;
  const int l = t & 63;
  const int w = t >> 6;
  const int lr = l & 15;
  const int kq = l >> 4;
  const long nbase = (long)blockIdx.x * BN;
  v8i af[2];
  float psq[2];
#pragma unroll
  for (int g = 0; g < 2; ++g) {
    const float* xr = X + (nbase + w * 32 + g * 16 + lr) * D + kq * 32;
    v8i av;
    float sq = 0.f;
#pragma unroll
    for (int j = 0; j < 8; ++j) {
      float4 v = *(const float4*)(xr + j * 4);
      sq = fmaf(v.x, v.x, sq);
      sq = fmaf(v.y, v.y, sq);
      sq = fmaf(v.z, v.z, sq);
      sq = fmaf(v.w, v.w, sq);
      av[j] = (int)(f2fp8_em(v.x) | (f2fp8_em(v.y) << 8) |
                    (f2fp8_em(v.z) << 16) | (f2fp8_em(v.w) << 24));
    }
    af[g] = av;
    psq[g] = sq;
  }
#pragma unroll
  for (int g = 0; g < 2; ++g) {
    float s2 = psq[g];
    s2 += __shfl_xor(s2, 16, 64);
    s2 += __shfl_xor(s2, 32, 64);
    if (kq == 0) x2s[w * 32 + g * 16 + lr] = s2;
  }
  {
    float4 v = ((const float4*)nm2)[t];
    *(float4*)(m2s + t * 4) = v;
  }
  float bs[8];
#pragma unroll
  for (int e = 0; e < 8; ++e) bs[e] = -3.402823466e38f;
  __syncthreads();
  const char* bbase = (const char*)mbf8 + l * 32;
  for (int ts = 0; ts < NT; ++ts) {
    const char* tp = bbase + ts * TILEB;
    const float* mp = m2s + ts * 64 + lr;
#pragma unroll
    for (int cgc = 0; cgc < 4; ++cgc) {
      const char* p = tp + cgc * 2048;
      BOp bu;
      bu.q[0] = *(const uint4*)(p);
      bu.q[1] = *(const uint4*)(p + 16);
      float m2v = mp[cgc * 16];
      f32x4 ci = {m2v, m2v, m2v, m2v};
#pragma unroll
      for (int g = 0; g < 2; ++g) {
        f32x4 acc = __builtin_amdgcn_mfma_scale_f32_16x16x128_f8f6f4(
            af[g], bu.v, ci, 0, 0, 0, 127, 0, 127);
#pragma unroll
        for (int e = 0; e < 4; ++e) bs[g * 4 + e] = fmaxf(bs[g * 4 + e], acc[e]);
      }
    }
  }
  float lsum = 0.f;
#pragma unroll
  for (int e = 0; e < 8; ++e) {
    float m = bs[e];
#pragma unroll
    for (int s = 1; s < 16; s <<= 1) {
      float o = __shfl_xor(m, s, 64);
      m = fmaxf(m, o);
    }
    if (lr == 0) {
      int rowc = (e >> 2) * 16 + kq * 4 + (e & 3);
      lsum += x2s[w * 32 + rowc] - 2.0f * m;
    }
  }
#pragma unroll
  for (int s = 32; s; s >>= 1) lsum += __shfl_down(lsum, s, 64);
  if (l == 0) wsum[w] = lsum;
  __syncthreads();
  if (t == 0) partials[blockIdx.x] = wsum[0] + wsum[1] + wsum[2] + wsum[3];
}

// Kernel 3: deterministic fixed-order final reduction (double accum).
__global__ void reduce_loss(const float* __restrict__ partials,
                            float* __restrict__ out) {
  __shared__ double ws[4];
  int t = threadIdx.x;
  double s = 0.0;
  for (int i = t; i < NBLK; i += 256) s += (double)partials[i];
#pragma unroll
  for (int m = 32; m; m >>= 1) s += __shfl_down(s, m, 64);
  if ((t & 63) == 0) ws[t >> 6] = s;
  __syncthreads();
  if (t == 0) out[0] = (float)(ws[0] + ws[1] + ws[2] + ws[3]);
}

extern "C" void kernel_launch(void* const* d_in, const int* in_sizes, int n_in,
                              void* d_out, int out_size, void* d_ws,
                              size_t ws_size, hipStream_t stream) {
  const float* X = (const float*)d_in[0];
  const float* means = (const float*)d_in[1];
  float* out = (float*)d_out;
  char* ws = (char*)d_ws;
  // layout: mbf8 128K | nm2 4K | partials 8K | x2 1M | xp 32M
  unsigned char* mbf8 = (unsigned char*)ws;
  float* nm2 = (float*)(ws + 131072);
  float* partials = (float*)(ws + 131072 + 4096);
  float* x2g = (float*)(ws + 131072 + 4096 + 8192);
  unsigned char* xp = (unsigned char*)(ws + 131072 + 4096 + 8192 + 1048576);
  const size_t needed = 131072 + 4096 + 8192 + 1048576 + (size_t)N_TOTAL * D;

  prep_means<<<K_TOTAL, 64, 0, stream>>>(means, mbf8, nm2);
  if (ws_size >= needed) {
    prep_x<<<NBLK, 256, 0, stream>>>(X, xp, x2g);
    kmeans_main<<<NBLK, 256, 0, stream>>>(xp, mbf8, nm2, x2g, partials);
  } else {
    kmeans_main_fb<<<NBLK, 256, 0, stream>>>(X, mbf8, nm2, partials);
  }
  reduce_loss<<<1, 256, 0, stream>>>(partials, out);
}

// Round 19
// 64.410 us; speedup vs baseline: 1.3882x; 1.3882x over previous
//
#include <hip/hip_runtime.h>
#include <hip/hip_fp8.h>

typedef int v8i __attribute__((ext_vector_type(8)));
typedef float f32x4 __attribute__((ext_vector_type(4)));

#define N_TOTAL 262144
#define D 128
#define K_TOTAL 1024
#define BN 256
#define NBLK (N_TOTAL / BN)  // 1024
#define TILEB 8192  // 64 centroids x 128 dims x 1 B fp8, 16x16x128-operand order
#define NT 16

// Kernel 1: codebook fp32 -> fp8 e4m3 (HW cvt_pk) in 16x16x128 B-operand
// order with q0/q1 SPLIT: within each cgc 2048B block, lane l's bytes 0..15
// live at l*16, bytes 16..31 at 1024 + l*16 (so each ds_read_b128 is a
// contiguous 1024B wave-read). nm2[k] = -0.5*||m||^2 exact fp32.
__global__ void prep_means(const float* __restrict__ means,
                           unsigned char* __restrict__ mbf8,
                           float* __restrict__ nm2) {
  int k = blockIdx.x, t = threadIdx.x;  // 1024 blocks x 64 threads
  int ts = k >> 6, c64 = k & 63;
  int cgc = c64 >> 4, c = c64 & 15;
  unsigned char* tb = mbf8 + ts * TILEB + cgc * 2048;
  float v0 = means[k * D + 2 * t];
  float v1 = means[k * D + 2 * t + 1];
  int d0 = 2 * t;
  int kq = d0 >> 5, rem0 = d0 & 31;
  int l = kq * 16 + c;
  int off = (rem0 < 16) ? (l * 16 + rem0) : (1024 + l * 16 + (rem0 - 16));
  int pk = __builtin_amdgcn_cvt_pk_fp8_f32(v0, v1, 0, false);
  *(unsigned short*)(tb + off) = (unsigned short)(pk & 0xFFFF);
  float s = v0 * v0 + v1 * v1;
#pragma unroll
  for (int m = 32; m; m >>= 1) s += __shfl_down(s, m, 64);
  if (t == 0) nm2[k] = -0.5f * s;
}

union BOp {
  uint4 q[2];
  v8i v;
};

// Kernel 2: r14 champion structure, 2x amortized. 256 rows/block, 4 waves x
// 64 rows (af[4], bs[16]). B tiles: T14 reg-staging (global->reg early,
// mid-tile ds_write) into linear LDS; split-q0/q1 ds_read_b128 (contiguous
// wave reads). HW cvt_pk A-conversion. loss = x2 - 2*max(score), exact fp32
// x2/m2, fp8 MX dots via mfma_scale_f32_16x16x128_f8f6f4.
__global__ __launch_bounds__(256) void kmeans_main(
    const float* __restrict__ X, const unsigned char* __restrict__ mbf8,
    const float* __restrict__ nm2, float* __restrict__ partials) {
  __shared__ __attribute__((aligned(16))) char Bs[2][TILEB];  // 16 KB dbuf
  __shared__ float m2s[K_TOTAL];                              // 4 KB
  __shared__ float x2s[BN];                                   // 1 KB
  __shared__ float wsum[4];

  const int t = threadIdx.x;
  const int l = t & 63;
  const int w = t >> 6;
  const int lr = l & 15;  // row-in-group (A) / centroid col (B/C)
  const int kq = l >> 4;  // k-quarter (32-float slice of D=128)
  const int rot = blockIdx.x & 15;
  const long nbase = (long)blockIdx.x * BN;

  // ---- A fragments (HW cvt_pk) + exact fp32 ||x||^2 partials ----
  v8i af[4];
  float psq[4];
#pragma unroll
  for (int g = 0; g < 4; ++g) {
    const float* xr = X + (nbase + w * 64 + g * 16 + lr) * D + kq * 32;
    v8i av;
    float sq = 0.f;
#pragma unroll
    for (int j = 0; j < 8; ++j) {
      float4 v = *(const float4*)(xr + j * 4);
      sq = fmaf(v.x, v.x, sq);
      sq = fmaf(v.y, v.y, sq);
      sq = fmaf(v.z, v.z, sq);
      sq = fmaf(v.w, v.w, sq);
      int lo = __builtin_amdgcn_cvt_pk_fp8_f32(v.x, v.y, 0, false);
      av[j] = __builtin_amdgcn_cvt_pk_fp8_f32(v.z, v.w, lo, true);
    }
    af[g] = av;
    psq[g] = sq;
  }
#pragma unroll
  for (int g = 0; g < 4; ++g) {
    float s2 = psq[g];
    s2 += __shfl_xor(s2, 16, 64);
    s2 += __shfl_xor(s2, 32, 64);
    if (kq == 0) x2s[w * 64 + g * 16 + lr] = s2;
  }

  // ---- stage nm2 into LDS (once) ----
  {
    float4 v = ((const float4*)nm2)[t];  // 256*4 = 1024
    *(float4*)(m2s + t * 4) = v;
  }

  float bs[16];  // running row maxes: [g*4 + reg]
#pragma unroll
  for (int e = 0; e < 16; ++e) bs[e] = -3.402823466e38f;

  // ---- prologue: stage tile `rot` (pure linear copy) ----
  {
    const char* src = (const char*)mbf8 + rot * TILEB;
    uint4 s0 = *(const uint4*)(src + t * 16);
    uint4 s1 = *(const uint4*)(src + 4096 + t * 16);
    *(uint4*)(Bs[0] + t * 16) = s0;
    *(uint4*)(Bs[0] + 4096 + t * 16) = s1;
  }
  __syncthreads();

#define COMPUTE_CGC(TID, BP, CGC)                                              \
  {                                                                            \
    float m2v_ = m2s[(TID) * 64 + (CGC) * 16 + lr];                            \
    f32x4 ci_ = {m2v_, m2v_, m2v_, m2v_};                                      \
    BOp bu_;                                                                   \
    bu_.q[0] = *(const uint4*)((BP) + (CGC) * 2048 + l * 16);                  \
    bu_.q[1] = *(const uint4*)((BP) + (CGC) * 2048 + 1024 + l * 16);           \
    _Pragma("unroll") for (int g_ = 0; g_ < 4; ++g_) {                         \
      f32x4 acc_ = __builtin_amdgcn_mfma_scale_f32_16x16x128_f8f6f4(           \
          af[g_], bu_.v, ci_, 0, 0, 0, 127, 0, 127);                           \
      _Pragma("unroll") for (int e_ = 0; e_ < 4; ++e_) {                       \
        bs[g_ * 4 + e_] = fmaxf(bs[g_ * 4 + e_], acc_[e_]);                    \
      }                                                                        \
    }                                                                          \
  }

  int cur = 0;
  for (int ks = 0; ks < NT; ++ks) {
    const int tid = (rot + ks) & 15;
    uint4 s0, s1;
    if (ks < NT - 1) {
      // issue next tile's global loads EARLY (latency hides under compute)
      const char* src = (const char*)mbf8 + (((rot + ks + 1) & 15) * TILEB);
      s0 = *(const uint4*)(src + t * 16);
      s1 = *(const uint4*)(src + 4096 + t * 16);
    }
    const char* bp = Bs[cur];
    COMPUTE_CGC(tid, bp, 0);
    COMPUTE_CGC(tid, bp, 1);
    if (ks < NT - 1) {
      // mid-tile write: staging regs die here; Bs[cur^1] not being read
      char* dst = Bs[cur ^ 1];
      *(uint4*)(dst + t * 16) = s0;
      *(uint4*)(dst + 4096 + t * 16) = s1;
    }
    COMPUTE_CGC(tid, bp, 2);
    COMPUTE_CGC(tid, bp, 3);
    __syncthreads();
    cur ^= 1;
  }
#undef COMPUTE_CGC

  // ---- per-row max across the 16 centroid-lanes, then loss contribution ----
  // slot (g, e) on lane (kq, lr) holds row g*16 + kq*4 + e (lanes lr share it)
  float lsum = 0.f;
#pragma unroll
  for (int e = 0; e < 16; ++e) {
    float m = bs[e];
#pragma unroll
    for (int s = 1; s < 16; s <<= 1) {
      float o = __shfl_xor(m, s, 64);
      m = fmaxf(m, o);
    }
    if (lr == 0) {
      int rowc = (e >> 2) * 16 + kq * 4 + (e & 3);
      lsum += x2s[w * 64 + rowc] - 2.0f * m;
    }
  }
#pragma unroll
  for (int s = 32; s; s >>= 1) lsum += __shfl_down(lsum, s, 64);
  if (l == 0) wsum[w] = lsum;
  __syncthreads();
  if (t == 0) partials[blockIdx.x] = wsum[0] + wsum[1] + wsum[2] + wsum[3];
}

// Kernel 3: deterministic fixed-order final reduction (double accum).
__global__ void reduce_loss(const float* __restrict__ partials,
                            float* __restrict__ out) {
  __shared__ double ws[4];
  int t = threadIdx.x;
  double s = 0.0;
  for (int i = t; i < NBLK; i += 256) s += (double)partials[i];
#pragma unroll
  for (int m = 32; m; m >>= 1) s += __shfl_down(s, m, 64);
  if ((t & 63) == 0) ws[t >> 6] = s;
  __syncthreads();
  if (t == 0) out[0] = (float)(ws[0] + ws[1] + ws[2] + ws[3]);
}

extern "C" void kernel_launch(void* const* d_in, const int* in_sizes, int n_in,
                              void* d_out, int out_size, void* d_ws,
                              size_t ws_size, hipStream_t stream) {
  const float* X = (const float*)d_in[0];
  const float* means = (const float*)d_in[1];
  float* out = (float*)d_out;
  char* ws = (char*)d_ws;
  unsigned char* mbf8 = (unsigned char*)ws;         // 131072 B
  float* nm2 = (float*)(ws + 131072);               // 4096 B
  float* partials = (float*)(ws + 131072 + 4096);   // 4096 B

  prep_means<<<K_TOTAL, 64, 0, stream>>>(means, mbf8, nm2);
  kmeans_main<<<NBLK, 256, 0, stream>>>(X, mbf8, nm2, partials);
  reduce_loss<<<1, 256, 0, stream>>>(partials, out);
}

// Round 20
// 60.494 us; speedup vs baseline: 1.4781x; 1.0647x over previous
//
#include <hip/hip_runtime.h>
#include <hip/hip_fp8.h>

typedef int v8i __attribute__((ext_vector_type(8)));
typedef float f32x4 __attribute__((ext_vector_type(4)));

#define N_TOTAL 262144
#define D 128
#define K_TOTAL 1024
#define BN 128
#define NBLK (N_TOTAL / BN)  // 2048
#define TILEB 8192  // 64 centroids x 128 dims x 1 B fp8, 16x16x128-operand order
#define NT 16

// Kernel 1: codebook fp32 -> fp8 e4m3 (HW cvt_pk) in 16x16x128 B-operand
// order with q0/q1 SPLIT (r19-verified): within each cgc 2048B block, lane
// l's bytes 0..15 at l*16, bytes 16..31 at 1024 + l*16 -> every ds_read_b128
// is a contiguous 1024B wave-read (0 bank conflicts). nm2[k] = -0.5||m||^2.
__global__ void prep_means(const float* __restrict__ means,
                           unsigned char* __restrict__ mbf8,
                           float* __restrict__ nm2) {
  int k = blockIdx.x, t = threadIdx.x;  // 1024 blocks x 64 threads
  int ts = k >> 6, c64 = k & 63;
  int cgc = c64 >> 4, c = c64 & 15;
  unsigned char* tb = mbf8 + ts * TILEB + cgc * 2048;
  float v0 = means[k * D + 2 * t];
  float v1 = means[k * D + 2 * t + 1];
  int d0 = 2 * t;
  int kq = d0 >> 5, rem0 = d0 & 31;
  int l = kq * 16 + c;
  int off = (rem0 < 16) ? (l * 16 + rem0) : (1024 + l * 16 + (rem0 - 16));
  int pk = __builtin_amdgcn_cvt_pk_fp8_f32(v0, v1, 0, false);
  *(unsigned short*)(tb + off) = (unsigned short)(pk & 0xFFFF);
  float s = v0 * v0 + v1 * v1;
#pragma unroll
  for (int m = 32; m; m >>= 1) s += __shfl_down(s, m, 64);
  if (t == 0) nm2[k] = -0.5f * s;
}

union BOp {
  uint4 q[2];
  v8i v;
};

// Kernel 2: r14 champion geometry (BN=128, 4 waves x 32 rows, grid 2048,
// ~52-60 VGPR residency band) + HW cvt_pk A-conversion (r17-verified) +
// split-q0/q1 conflict-free LDS reads (r19-verified). T14 reg-staging with
// mid-tile ds_write. loss = x2 - 2*max_k(x.m - 0.5||m||^2); exact fp32
// x2/m2; fp8 MX dots via mfma_scale_f32_16x16x128_f8f6f4.
__global__ __launch_bounds__(256) void kmeans_main(
    const float* __restrict__ X, const unsigned char* __restrict__ mbf8,
    const float* __restrict__ nm2, float* __restrict__ partials) {
  __shared__ __attribute__((aligned(16))) char Bs[2][TILEB];  // 16 KB dbuf
  __shared__ float m2s[K_TOTAL];                              // 4 KB
  __shared__ float x2s[BN];                                   // 512 B
  __shared__ float wsum[4];

  const int t = threadIdx.x;
  const int l = t & 63;
  const int w = t >> 6;
  const int lr = l & 15;  // row-in-group (A) / centroid col (B/C)
  const int kq = l >> 4;  // k-quarter (32-float slice of D=128)
  const int rot = blockIdx.x & 15;
  const long nbase = (long)blockIdx.x * BN;

  // ---- A fragments (HW cvt_pk) + exact fp32 ||x||^2 partials ----
  v8i af[2];
  float psq[2];
#pragma unroll
  for (int g = 0; g < 2; ++g) {
    const float* xr = X + (nbase + w * 32 + g * 16 + lr) * D + kq * 32;
    v8i av;
    float sq = 0.f;
#pragma unroll
    for (int j = 0; j < 8; ++j) {
      float4 v = *(const float4*)(xr + j * 4);
      sq = fmaf(v.x, v.x, sq);
      sq = fmaf(v.y, v.y, sq);
      sq = fmaf(v.z, v.z, sq);
      sq = fmaf(v.w, v.w, sq);
      int lo = __builtin_amdgcn_cvt_pk_fp8_f32(v.x, v.y, 0, false);
      av[j] = __builtin_amdgcn_cvt_pk_fp8_f32(v.z, v.w, lo, true);
    }
    af[g] = av;
    psq[g] = sq;
  }
#pragma unroll
  for (int g = 0; g < 2; ++g) {
    float s2 = psq[g];
    s2 += __shfl_xor(s2, 16, 64);
    s2 += __shfl_xor(s2, 32, 64);
    if (kq == 0) x2s[w * 32 + g * 16 + lr] = s2;
  }

  // ---- stage nm2 into LDS (once) ----
  {
    float4 v = ((const float4*)nm2)[t];  // 256*4 = 1024
    *(float4*)(m2s + t * 4) = v;
  }

  float bs[8];  // running row maxes: [g*4 + reg]
#pragma unroll
  for (int e = 0; e < 8; ++e) bs[e] = -3.402823466e38f;

  // ---- prologue: stage tile `rot` (pure linear copy) ----
  {
    const char* src = (const char*)mbf8 + rot * TILEB;
    uint4 s0 = *(const uint4*)(src + t * 16);
    uint4 s1 = *(const uint4*)(src + 4096 + t * 16);
    *(uint4*)(Bs[0] + t * 16) = s0;
    *(uint4*)(Bs[0] + 4096 + t * 16) = s1;
  }
  __syncthreads();

#define COMPUTE_CGC(TID, BP, CGC)                                              \
  {                                                                            \
    float m2v_ = m2s[(TID) * 64 + (CGC) * 16 + lr];                            \
    f32x4 ci_ = {m2v_, m2v_, m2v_, m2v_};                                      \
    BOp bu_;                                                                   \
    bu_.q[0] = *(const uint4*)((BP) + (CGC) * 2048 + l * 16);                  \
    bu_.q[1] = *(const uint4*)((BP) + (CGC) * 2048 + 1024 + l * 16);           \
    _Pragma("unroll") for (int g_ = 0; g_ < 2; ++g_) {                         \
      f32x4 acc_ = __builtin_amdgcn_mfma_scale_f32_16x16x128_f8f6f4(           \
          af[g_], bu_.v, ci_, 0, 0, 0, 127, 0, 127);                           \
      _Pragma("unroll") for (int e_ = 0; e_ < 4; ++e_) {                       \
        bs[g_ * 4 + e_] = fmaxf(bs[g_ * 4 + e_], acc_[e_]);                    \
      }                                                                        \
    }                                                                          \
  }

  int cur = 0;
  for (int ks = 0; ks < NT; ++ks) {
    const int tid = (rot + ks) & 15;
    uint4 s0, s1;
    if (ks < NT - 1) {
      // issue next tile's global loads EARLY (latency hides under compute)
      const char* src = (const char*)mbf8 + (((rot + ks + 1) & 15) * TILEB);
      s0 = *(const uint4*)(src + t * 16);
      s1 = *(const uint4*)(src + 4096 + t * 16);
    }
    const char* bp = Bs[cur];
    COMPUTE_CGC(tid, bp, 0);
    COMPUTE_CGC(tid, bp, 1);
    if (ks < NT - 1) {
      // mid-tile write: staging regs die here; Bs[cur^1] not being read
      char* dst = Bs[cur ^ 1];
      *(uint4*)(dst + t * 16) = s0;
      *(uint4*)(dst + 4096 + t * 16) = s1;
    }
    COMPUTE_CGC(tid, bp, 2);
    COMPUTE_CGC(tid, bp, 3);
    __syncthreads();
    cur ^= 1;
  }
#undef COMPUTE_CGC

  // ---- per-row max across the 16 centroid-lanes, then loss contribution ----
  // slot (g, e) on lane (kq, lr) holds row g*16 + kq*4 + e (lanes lr share it)
  float lsum = 0.f;
#pragma unroll
  for (int e = 0; e < 8; ++e) {
    float m = bs[e];
#pragma unroll
    for (int s = 1; s < 16; s <<= 1) {
      float o = __shfl_xor(m, s, 64);
      m = fmaxf(m, o);
    }
    if (lr == 0) {
      int rowc = (e >> 2) * 16 + kq * 4 + (e & 3);
      lsum += x2s[w * 32 + rowc] - 2.0f * m;
    }
  }
#pragma unroll
  for (int s = 32; s; s >>= 1) lsum += __shfl_down(lsum, s, 64);
  if (l == 0) wsum[w] = lsum;
  __syncthreads();
  if (t == 0) partials[blockIdx.x] = wsum[0] + wsum[1] + wsum[2] + wsum[3];
}

// Kernel 3: deterministic fixed-order final reduction (double accum).
__global__ void reduce_loss(const float* __restrict__ partials,
                            float* __restrict__ out) {
  __shared__ double ws[4];
  int t = threadIdx.x;
  double s = 0.0;
  for (int i = t; i < NBLK; i += 256) s += (double)partials[i];
#pragma unroll
  for (int m = 32; m; m >>= 1) s += __shfl_down(s, m, 64);
  if ((t & 63) == 0) ws[t >> 6] = s;
  __syncthreads();
  if (t == 0) out[0] = (float)(ws[0] + ws[1] + ws[2] + ws[3]);
}

extern "C" void kernel_launch(void* const* d_in, const int* in_sizes, int n_in,
                              void* d_out, int out_size, void* d_ws,
                              size_t ws_size, hipStream_t stream) {
  const float* X = (const float*)d_in[0];
  const float* means = (const float*)d_in[1];
  float* out = (float*)d_out;
  char* ws = (char*)d_ws;
  unsigned char* mbf8 = (unsigned char*)ws;         // 131072 B
  float* nm2 = (float*)(ws + 131072);               // 4096 B
  float* partials = (float*)(ws + 131072 + 4096);   // 8192 B

  prep_means<<<K_TOTAL, 64, 0, stream>>>(means, mbf8, nm2);
  kmeans_main<<<NBLK, 256, 0, stream>>>(X, mbf8, nm2, partials);
  reduce_loss<<<1, 256, 0, stream>>>(partials, out);
}